// Round 1
// baseline (248.437 us; speedup 1.0000x reference)
//
#include <hip/hip_runtime.h>
#include <stdint.h>

#define N_SEQ 4096

typedef float f32x4 __attribute__((ext_vector_type(4)));
typedef unsigned short u16x8 __attribute__((ext_vector_type(8)));
typedef __bf16 bf16x8 __attribute__((ext_vector_type(8)));

static __device__ __forceinline__ unsigned short f2bf(float f) {
    unsigned u = __builtin_bit_cast(unsigned, f);
    u += 0x7fffu + ((u >> 16) & 1u);
    return (unsigned short)(u >> 16);
}

// ---------------- Kernel 1: QKV projection (fp32 GEMM, bf16 out) ----------------
// x[16384][128] @ Wq[128][384] + bq -> Q[bh][n][32], K[bh][n][32], V^T[bh][32][n] (bf16)
// col c of 384: h = c/96, d = (c%96)/3, s = c%3 (qkv innermost)
__global__ __launch_bounds__(256) void qkv_kernel(
    const float* __restrict__ x, const float* __restrict__ Wq,
    const float* __restrict__ bq, unsigned short* __restrict__ Qo,
    unsigned short* __restrict__ Ko, unsigned short* __restrict__ VTo)
{
    __shared__ __align__(16) float xT[128][68];   // [k][row], padded stride
    const int tid = threadIdx.x;
    const long r0 = (long)blockIdx.x * 64;
    #pragma unroll
    for (int i = 0; i < 32; ++i) {
        int flat = i * 256 + tid;
        int row = flat >> 7, kk = flat & 127;
        xT[kk][row] = x[(r0 + row) * 128 + kk];
    }
    __syncthreads();
    const int rg = tid & 3, cb = tid >> 2;   // 16 rows x 6 cols per thread
    float acc[6][16];
    #pragma unroll
    for (int j = 0; j < 6; ++j)
        #pragma unroll
        for (int r = 0; r < 16; ++r) acc[j][r] = 0.f;

    for (int kk = 0; kk < 128; ++kk) {
        float xr[16];
        #pragma unroll
        for (int q = 0; q < 4; ++q) {
            f32x4 v = *(const f32x4*)&xT[kk][rg * 16 + 4 * q];  // broadcast reads
            xr[4*q+0] = v[0]; xr[4*q+1] = v[1]; xr[4*q+2] = v[2]; xr[4*q+3] = v[3];
        }
        float wv[6];
        #pragma unroll
        for (int j = 0; j < 6; ++j) wv[j] = Wq[kk * 384 + cb + 64 * j];
        #pragma unroll
        for (int j = 0; j < 6; ++j)
            #pragma unroll
            for (int r = 0; r < 16; ++r) acc[j][r] = fmaf(xr[r], wv[j], acc[j][r]);
    }
    #pragma unroll
    for (int j = 0; j < 6; ++j) {
        int c = cb + 64 * j;
        int h = c / 96;
        int d = (c % 96) / 3;
        int s = c % 3;
        float bias = bq[c];
        #pragma unroll
        for (int r = 0; r < 16; ++r) {
            long n = r0 + rg * 16 + r;
            int bb = (int)(n >> 12), nn = (int)(n & 4095);
            int bh = bb * 4 + h;
            unsigned short bits = f2bf(acc[j][r] + bias);
            if (s == 0)      Qo[((long)bh * 4096 + nn) * 32 + d] = bits;
            else if (s == 1) Ko[((long)bh * 4096 + nn) * 32 + d] = bits;
            else             VTo[((long)bh * 32 + d) * 4096 + nn] = bits;
        }
    }
}

// ---------------- Kernel 2: flash attention (bf16 MFMA 16x16x32) ----------------
// grid (32 q-tiles, 16 bh), 256 thr = 4 waves x 32 q-rows; KV tiles of 64.
__global__ __launch_bounds__(256, 2) void attn_kernel(
    const unsigned short* __restrict__ Q, const unsigned short* __restrict__ K,
    const unsigned short* __restrict__ VT, unsigned short* __restrict__ AO)
{
    __shared__ __align__(16) unsigned short K_lds[64 * 32];    // [kv][d], chunk-swizzled
    __shared__ __align__(16) unsigned short Vt_lds[32 * 64];   // [d][kv], chunk-swizzled
    __shared__ __align__(16) unsigned short P_lds[4][32 * 64]; // per-wave [qrow][kv]

    const int tid  = threadIdx.x;
    const int lane = tid & 63;
    const int w    = tid >> 6;
    const int g    = lane >> 4;
    const int lo   = lane & 15;

    const int bh = blockIdx.y;
    const int q0 = blockIdx.x * 128 + w * 32;
    const long base = (long)bh * N_SEQ * 32;

    const float SL = 0.08838834764831845f * 1.4426950408889634f; // (1/sqrt(128))*log2(e)

    // Q fragments in registers (A operand: row = lo, k-chunk = g)
    bf16x8 qf[2];
    #pragma unroll
    for (int rt = 0; rt < 2; ++rt) {
        const unsigned short* p = Q + base + (long)(q0 + rt * 16 + lo) * 32 + g * 8;
        qf[rt] = __builtin_bit_cast(bf16x8, *(const u16x8*)p);
    }
    bf16x8 onesf;
    {
        u16x8 ou = {0x3F80,0x3F80,0x3F80,0x3F80,0x3F80,0x3F80,0x3F80,0x3F80};
        onesf = __builtin_bit_cast(bf16x8, ou);
    }
    const f32x4 zf = {0.f, 0.f, 0.f, 0.f};
    f32x4 o_[2][2] = {{zf, zf}, {zf, zf}};
    f32x4 ls[2]    = {zf, zf};
    float mrun[2][4] = {{-1e30f,-1e30f,-1e30f,-1e30f},{-1e30f,-1e30f,-1e30f,-1e30f}};

    // staging coords (reg-staging, swizzled ds_write_b128: conflict-free)
    const int krow = w * 16 + (lane >> 2);
    const int kch  = lane & 3;
    const int kwch = kch ^ ((krow >> 1) & 3);
    const int vrow = w * 8 + (lane >> 3);
    const int vch  = lane & 7;
    const int vwch = vch ^ (vrow & 7);
    const unsigned short* ksrc = K  + base + (long)krow * 32 + kch * 8;
    const unsigned short* vsrc = VT + base + (long)vrow * N_SEQ + vch * 8;
    unsigned short* kdst = &K_lds[krow * 32 + kwch * 8];
    unsigned short* vdst = &Vt_lds[vrow * 64 + vwch * 8];
    unsigned short* Pw   = &P_lds[w][0];

    u16x8 kreg = *(const u16x8*)ksrc;
    u16x8 vreg = *(const u16x8*)vsrc;

    #pragma unroll 1
    for (int t = 0; t < N_SEQ / 64; ++t) {
        __syncthreads();                   // all waves done reading prev tile
        *(u16x8*)kdst = kreg;
        *(u16x8*)vdst = vreg;
        __syncthreads();                   // tile visible
        // prefetch next tile right away (hidden under compute)
        ksrc += 64 * 32;
        vsrc += 64;
        kreg = *(const u16x8*)ksrc;        // last iter reads in-bounds scratch, discarded
        vreg = *(const u16x8*)vsrc;

        // S = Q K^T  (raw, scale folded into exp2)
        f32x4 s[2][4];
        #pragma unroll
        for (int ct = 0; ct < 4; ++ct) {
            int row = lo + 16 * ct;
            int pc  = g ^ ((row >> 1) & 3);
            bf16x8 kf = __builtin_bit_cast(bf16x8, *(const u16x8*)&K_lds[row * 32 + pc * 8]);
            s[0][ct] = __builtin_amdgcn_mfma_f32_16x16x32_bf16(qf[0], kf, zf, 0, 0, 0);
            s[1][ct] = __builtin_amdgcn_mfma_f32_16x16x32_bf16(qf[1], kf, zf, 0, 0, 0);
        }
        // online softmax (C/D layout: row = rt*16 + 4g + j, col = lo + 16ct)
        #pragma unroll
        for (int rt = 0; rt < 2; ++rt) {
            float mn_[4], al_[4];
            #pragma unroll
            for (int j = 0; j < 4; ++j) {
                float rm = fmaxf(fmaxf(s[rt][0][j], s[rt][1][j]),
                                 fmaxf(s[rt][2][j], s[rt][3][j]));
                rm = fmaxf(rm, __shfl_xor(rm, 1));
                rm = fmaxf(rm, __shfl_xor(rm, 2));
                rm = fmaxf(rm, __shfl_xor(rm, 4));
                rm = fmaxf(rm, __shfl_xor(rm, 8));
                float mo = mrun[rt][j];
                float mn = fmaxf(mo, rm);
                al_[j] = exp2f((mo - mn) * SL);
                mn_[j] = mn;
                mrun[rt][j] = mn;
            }
            #pragma unroll
            for (int j = 0; j < 4; ++j) {
                ls[rt][j]    *= al_[j];
                o_[rt][0][j] *= al_[j];
                o_[rt][1][j] *= al_[j];
            }
            #pragma unroll
            for (int ct = 0; ct < 4; ++ct) {
                int col = lo + 16 * ct;
                #pragma unroll
                for (int j = 0; j < 4; ++j) {
                    int row = rt * 16 + 4 * g + j;
                    float p = exp2f((s[rt][ct][j] - mn_[j]) * SL);
                    int ch = (col >> 3) ^ (row & 7);
                    Pw[row * 64 + ch * 8 + (col & 7)] = f2bf(p);
                }
            }
        }
        __builtin_amdgcn_sched_barrier(0); // keep P reads after P writes (same-wave LDS order)
        // O += P V ; row-sum via ones-MFMA (each lane gets exactly its rows' sums)
        #pragma unroll
        for (int kk = 0; kk < 2; ++kk) {
            bf16x8 pa[2];
            #pragma unroll
            for (int rt = 0; rt < 2; ++rt) {
                int row = rt * 16 + lo;
                int ch  = (4 * kk + g) ^ (row & 7);
                pa[rt] = __builtin_bit_cast(bf16x8, *(const u16x8*)&Pw[row * 64 + ch * 8]);
            }
            ls[0] = __builtin_amdgcn_mfma_f32_16x16x32_bf16(pa[0], onesf, ls[0], 0, 0, 0);
            ls[1] = __builtin_amdgcn_mfma_f32_16x16x32_bf16(pa[1], onesf, ls[1], 0, 0, 0);
            #pragma unroll
            for (int dt = 0; dt < 2; ++dt) {
                int dr = lo + 16 * dt;
                int ch = (4 * kk + g) ^ (dr & 7);
                bf16x8 vb = __builtin_bit_cast(bf16x8, *(const u16x8*)&Vt_lds[dr * 64 + ch * 8]);
                o_[0][dt] = __builtin_amdgcn_mfma_f32_16x16x32_bf16(pa[0], vb, o_[0][dt], 0, 0, 0);
                o_[1][dt] = __builtin_amdgcn_mfma_f32_16x16x32_bf16(pa[1], vb, o_[1][dt], 0, 0, 0);
            }
        }
    }
    // epilogue: normalize and write attn output bf16 [b][n][h*32+d]
    const int bb = bh >> 2, h = bh & 3;
    #pragma unroll
    for (int rt = 0; rt < 2; ++rt)
        #pragma unroll
        for (int dt = 0; dt < 2; ++dt)
            #pragma unroll
            for (int j = 0; j < 4; ++j) {
                int row = q0 + rt * 16 + 4 * g + j;
                int e = h * 32 + lo + 16 * dt;
                float val = o_[rt][dt][j] / ls[rt][j];
                AO[((long)bb * N_SEQ + row) * 128 + e] = f2bf(val);
            }
}

// ---------------- Kernel 3: output projection (fp32 GEMM + bias) ----------------
__global__ __launch_bounds__(256) void proj_kernel(
    const unsigned short* __restrict__ ain, const float* __restrict__ Wp,
    const float* __restrict__ bp, float* __restrict__ out)
{
    __shared__ __align__(16) float xT[128][68];
    const int tid = threadIdx.x;
    const long r0 = (long)blockIdx.x * 64;
    #pragma unroll
    for (int i = 0; i < 32; ++i) {
        int flat = i * 256 + tid;
        int row = flat >> 7, kk = flat & 127;
        unsigned int ub = ain[(r0 + row) * 128 + kk];
        xT[kk][row] = __builtin_bit_cast(float, ub << 16);
    }
    __syncthreads();
    const int rg = tid & 3, cb = tid >> 2;   // 16 rows x 2 cols per thread
    float acc0[16], acc1[16];
    #pragma unroll
    for (int r = 0; r < 16; ++r) { acc0[r] = 0.f; acc1[r] = 0.f; }
    for (int kk = 0; kk < 128; ++kk) {
        float xr[16];
        #pragma unroll
        for (int q = 0; q < 4; ++q) {
            f32x4 v = *(const f32x4*)&xT[kk][rg * 16 + 4 * q];
            xr[4*q+0] = v[0]; xr[4*q+1] = v[1]; xr[4*q+2] = v[2]; xr[4*q+3] = v[3];
        }
        float w0 = Wp[kk * 128 + cb];
        float w1 = Wp[kk * 128 + cb + 64];
        #pragma unroll
        for (int r = 0; r < 16; ++r) {
            acc0[r] = fmaf(xr[r], w0, acc0[r]);
            acc1[r] = fmaf(xr[r], w1, acc1[r]);
        }
    }
    float b0 = bp[cb], b1 = bp[cb + 64];
    #pragma unroll
    for (int r = 0; r < 16; ++r) {
        long n = r0 + rg * 16 + r;
        out[n * 128 + cb]      = acc0[r] + b0;
        out[n * 128 + cb + 64] = acc1[r] + b1;
    }
}

extern "C" void kernel_launch(void* const* d_in, const int* in_sizes, int n_in,
                              void* d_out, int out_size, void* d_ws, size_t ws_size,
                              hipStream_t stream)
{
    const float* x  = (const float*)d_in[0];
    const float* Wq = (const float*)d_in[1];
    const float* bq = (const float*)d_in[2];
    const float* Wp = (const float*)d_in[3];
    const float* bp = (const float*)d_in[4];
    float* out = (float*)d_out;

    // workspace: Q (4MB) | K (4MB) | V^T (4MB) | attn-out (4MB), all bf16
    unsigned short* Qw  = (unsigned short*)d_ws;
    unsigned short* Kw  = Qw  + (size_t)16 * 4096 * 32;
    unsigned short* VTw = Kw  + (size_t)16 * 4096 * 32;
    unsigned short* AOw = VTw + (size_t)16 * 4096 * 32;

    qkv_kernel<<<256, 256, 0, stream>>>(x, Wq, bq, Qw, Kw, VTw);
    attn_kernel<<<dim3(32, 16), 256, 0, stream>>>(Qw, Kw, VTw, AOw);
    proj_kernel<<<256, 256, 0, stream>>>(AOw, Wp, bp, out);
}

// Round 2
// 137.113 us; speedup vs baseline: 1.8119x; 1.8119x over previous
//
#include <hip/hip_runtime.h>
#include <stdint.h>

#define N_SEQ 4096

typedef float f32x4 __attribute__((ext_vector_type(4)));
typedef float f32x2 __attribute__((ext_vector_type(2)));
typedef unsigned short u16x8 __attribute__((ext_vector_type(8)));
typedef __bf16 bf16x8 __attribute__((ext_vector_type(8)));
typedef __bf16 bf16x4 __attribute__((ext_vector_type(4)));

static __device__ __forceinline__ float bf2f(unsigned short u) {
    unsigned v = ((unsigned)u) << 16;
    return __builtin_bit_cast(float, v);
}

// ---------------- Kernel 1: QKV projection (fp32 GEMM, bf16 out) ----------------
// x[16384][128] @ Wq[128][384] + bq.
// Q  -> natural [bh][n][32]
// KF -> fragment-ready: KF[((bh*64+t)*4+ct)*512 + l*8 + i] = K[bh][64t+(l&15)+16ct][(l>>4)*8+i]
// VF -> fragment-ready (pos-permuted kv): pos(kv)=((kv&15)<<2)|(kv>>4);
//       VF[(((bh*64+t)*2+kk)*2+dt)*512 + l*8 + i] = V[bh][64t+kv][ (l&15)+16dt ],
//       where pos = kk*32 + (l>>4)*8 + i
__global__ __launch_bounds__(256) void qkv_kernel(
    const float* __restrict__ x, const float* __restrict__ Wq,
    const float* __restrict__ bq, unsigned short* __restrict__ Qo,
    unsigned short* __restrict__ KFo, unsigned short* __restrict__ VFo)
{
    __shared__ __align__(16) float xT[128][36];   // [k][row]
    const int tid = threadIdx.x;
    const long r0 = (long)blockIdx.x * 32;
    #pragma unroll
    for (int i = 0; i < 4; ++i) {
        int idx = i * 256 + tid;                   // 1024 float4 tiles
        int row = idx >> 5, kc = (idx & 31) * 4;
        f32x4 v = *(const f32x4*)&x[(r0 + row) * 128 + kc];
        xT[kc + 0][row] = v[0]; xT[kc + 1][row] = v[1];
        xT[kc + 2][row] = v[2]; xT[kc + 3][row] = v[3];
    }
    __syncthreads();
    const int r8 = (tid >> 6) * 8;    // 8-row group
    const int c6 = (tid & 63) * 6;    // 6 consecutive cols
    float acc[6][8];
    #pragma unroll
    for (int j = 0; j < 6; ++j)
        #pragma unroll
        for (int r = 0; r < 8; ++r) acc[j][r] = 0.f;

    for (int k = 0; k < 128; ++k) {
        f32x4 a0 = *(const f32x4*)&xT[k][r8];      // wave-uniform broadcast
        f32x4 a1 = *(const f32x4*)&xT[k][r8 + 4];
        float xr[8] = {a0[0],a0[1],a0[2],a0[3],a1[0],a1[1],a1[2],a1[3]};
        float wv[6];
        #pragma unroll
        for (int u = 0; u < 3; ++u) {
            f32x2 wp = *(const f32x2*)&Wq[k * 384 + c6 + 2 * u];
            wv[2*u] = wp[0]; wv[2*u+1] = wp[1];
        }
        #pragma unroll
        for (int j = 0; j < 6; ++j)
            #pragma unroll
            for (int r = 0; r < 8; ++r) acc[j][r] = fmaf(xr[r], wv[j], acc[j][r]);
    }
    #pragma unroll
    for (int j = 0; j < 6; ++j) {
        int col = c6 + j;
        int h = col / 96, rem = col % 96;
        int d = rem / 3, s = rem % 3;
        float bias = bq[col];
        #pragma unroll
        for (int r = 0; r < 8; ++r) {
            long n = r0 + r8 + r;
            int bb = (int)(n >> 12), nn = (int)(n & 4095);
            int bh = bb * 4 + h;
            int t = nn >> 6, kvi = nn & 63;
            unsigned short bits = __builtin_bit_cast(unsigned short, (__bf16)(acc[j][r] + bias));
            if (s == 0) {
                Qo[((long)bh * 4096 + nn) * 32 + d] = bits;
            } else if (s == 1) {
                int ct = kvi >> 4, lo16 = kvi & 15;
                int gg = d >> 3, ii = d & 7;
                int l = gg * 16 + lo16;
                KFo[(long)(((bh * 64 + t) * 4 + ct) * 512) + l * 8 + ii] = bits;
            } else {
                int pos = ((kvi & 15) << 2) | (kvi >> 4);
                int kk = pos >> 5, lg = (pos >> 3) & 3, ii = pos & 7;
                int l = lg * 16 + (d & 15);
                int dt = d >> 4;
                VFo[(long)((((bh * 64 + t) * 2 + kk) * 2 + dt) * 512) + l * 8 + ii] = bits;
            }
        }
    }
}

// ---------------- Kernel 2: flash attention, no staging, no barriers ----------------
// 512 blocks x 256 thr = 4 independent waves/block, each wave: 32 q-rows, all 4096 kv.
#define MFMA16 __builtin_amdgcn_mfma_f32_16x16x32_bf16

__global__ __launch_bounds__(256, 2) void attn_kernel(
    const unsigned short* __restrict__ Q, const unsigned short* __restrict__ KF,
    const unsigned short* __restrict__ VF, unsigned short* __restrict__ AO)
{
    __shared__ __align__(16) unsigned short P_lds[4][32 * 64]; // per-wave, chunk-swizzled

    const int tid = threadIdx.x, lane = tid & 63, w = tid >> 6;
    const int g = lane >> 4, lo = lane & 15;

    // bijective XCD swizzle: consecutive-mod-8 blocks (same XCD) share bh
    const int bid = blockIdx.x;
    const int vid = (bid & 7) * 64 + (bid >> 3);
    const int qi = vid & 31, bh = vid >> 5;
    const int q0 = qi * 128 + w * 32;

    const float SL = (float)(0.08838834764831845 * 1.4426950408889634);

    bf16x8 qf[2];
    #pragma unroll
    for (int rt = 0; rt < 2; ++rt) {
        const unsigned short* p = Q + ((long)bh * 4096 + q0 + rt * 16 + lo) * 32 + g * 8;
        qf[rt] = __builtin_bit_cast(bf16x8, *(const u16x8*)p);
    }
    bf16x8 onesf;
    {
        u16x8 ou = {0x3F80,0x3F80,0x3F80,0x3F80,0x3F80,0x3F80,0x3F80,0x3F80};
        onesf = __builtin_bit_cast(bf16x8, ou);
    }
    const f32x4 zf = {0.f, 0.f, 0.f, 0.f};
    f32x4 o_[2][2] = {{zf, zf}, {zf, zf}};
    f32x4 ls[2]    = {zf, zf};

    const u16x8* kp = (const u16x8*)KF + (long)bh * 64 * 256 + lane; // 256 u16x8 per tile
    const u16x8* vp = (const u16x8*)VF + (long)bh * 64 * 256 + lane;

    unsigned short* Pw = P_lds[w];
    const int pc0 = g ^ (lo & 7);        // pa-read chunk base
    const int wc0 = (lo >> 1) ^ (4 * (g & 1)); // P-write chunk base

    u16x8 ka[4], va[4], kb[4], vb_[4];
    #pragma unroll
    for (int i = 0; i < 4; ++i) { ka[i] = kp[i * 64]; va[i] = vp[i * 64]; }

#define COMPUTE(KARR, VARR) do {                                               \
    f32x4 s_[2][4];                                                            \
    _Pragma("unroll")                                                          \
    for (int ct = 0; ct < 4; ++ct) {                                           \
        bf16x8 kfr = __builtin_bit_cast(bf16x8, KARR[ct]);                     \
        s_[0][ct] = MFMA16(qf[0], kfr, zf, 0, 0, 0);                           \
        s_[1][ct] = MFMA16(qf[1], kfr, zf, 0, 0, 0);                           \
    }                                                                          \
    _Pragma("unroll")                                                          \
    for (int rt = 0; rt < 2; ++rt) {                                           \
        _Pragma("unroll")                                                      \
        for (int j = 0; j < 4; ++j) {                                          \
            float p0 = exp2f(fminf(s_[rt][0][j] * SL, 60.f));                  \
            float p1 = exp2f(fminf(s_[rt][1][j] * SL, 60.f));                  \
            float p2 = exp2f(fminf(s_[rt][2][j] * SL, 60.f));                  \
            float p3 = exp2f(fminf(s_[rt][3][j] * SL, 60.f));                  \
            bf16x4 pv = { (__bf16)p0, (__bf16)p1, (__bf16)p2, (__bf16)p3 };    \
            int r_ = 16 * rt + 4 * g + j;                                      \
            int ch_ = wc0 ^ j;                                                 \
            *(bf16x4*)&Pw[r_ * 64 + ch_ * 8 + (lo & 1) * 4] = pv;              \
        }                                                                      \
    }                                                                          \
    __builtin_amdgcn_sched_barrier(0);                                        \
    _Pragma("unroll")                                                          \
    for (int kk = 0; kk < 2; ++kk) {                                           \
        _Pragma("unroll")                                                      \
        for (int rt = 0; rt < 2; ++rt) {                                       \
            bf16x8 pa = __builtin_bit_cast(bf16x8,                             \
                *(const u16x8*)&Pw[(16 * rt + lo) * 64 + (pc0 ^ (4 * kk)) * 8]);\
            ls[rt] = MFMA16(pa, onesf, ls[rt], 0, 0, 0);                       \
            o_[rt][0] = MFMA16(pa, __builtin_bit_cast(bf16x8, VARR[kk*2+0]),   \
                               o_[rt][0], 0, 0, 0);                            \
            o_[rt][1] = MFMA16(pa, __builtin_bit_cast(bf16x8, VARR[kk*2+1]),   \
                               o_[rt][1], 0, 0, 0);                            \
        }                                                                      \
    }                                                                          \
} while (0)

    #pragma unroll 1
    for (int t = 0; t < 64; t += 2) {
        kp += 256; vp += 256;
        #pragma unroll
        for (int i = 0; i < 4; ++i) { kb[i] = kp[i * 64]; vb_[i] = vp[i * 64]; }
        COMPUTE(ka, va);
        kp += 256; vp += 256;   // t=62: reads 1 tile past end -> lands in next ws buffer (discarded)
        #pragma unroll
        for (int i = 0; i < 4; ++i) { ka[i] = kp[i * 64]; va[i] = vp[i * 64]; }
        COMPUTE(kb, vb_);
    }
#undef COMPUTE

    // epilogue: AO[b][n][h*32+d] bf16
    const int bb = bh >> 2, h = bh & 3;
    #pragma unroll
    for (int rt = 0; rt < 2; ++rt)
        #pragma unroll
        for (int dt = 0; dt < 2; ++dt)
            #pragma unroll
            for (int j = 0; j < 4; ++j) {
                int row = q0 + rt * 16 + 4 * g + j;
                int e = h * 32 + lo + 16 * dt;
                float val = o_[rt][dt][j] / ls[rt][j];
                AO[((long)bb * N_SEQ + row) * 128 + e] =
                    __builtin_bit_cast(unsigned short, (__bf16)val);
            }
}

// ---------------- Kernel 3: output projection (fp32 GEMM + bias) ----------------
__global__ __launch_bounds__(256) void proj_kernel(
    const unsigned short* __restrict__ ain, const float* __restrict__ Wp,
    const float* __restrict__ bp, float* __restrict__ out)
{
    __shared__ __align__(16) float xT[128][36];
    const int tid = threadIdx.x;
    const long r0 = (long)blockIdx.x * 32;
    #pragma unroll
    for (int i = 0; i < 2; ++i) {
        int idx = i * 256 + tid;                 // 512 x u16x8
        int row = idx >> 4, kc = (idx & 15) * 8;
        u16x8 v = *(const u16x8*)&ain[(r0 + row) * 128 + kc];
        #pragma unroll
        for (int e = 0; e < 8; ++e) xT[kc + e][row] = bf2f(v[e]);
    }
    __syncthreads();
    const int r8 = (tid >> 6) * 8;
    const int c  = tid & 63;
    float acc0[8], acc1[8];
    #pragma unroll
    for (int r = 0; r < 8; ++r) { acc0[r] = 0.f; acc1[r] = 0.f; }
    for (int k = 0; k < 128; ++k) {
        f32x4 a0 = *(const f32x4*)&xT[k][r8];
        f32x4 a1 = *(const f32x4*)&xT[k][r8 + 4];
        float xr[8] = {a0[0],a0[1],a0[2],a0[3],a1[0],a1[1],a1[2],a1[3]};
        float w0 = Wp[k * 128 + c];
        float w1 = Wp[k * 128 + c + 64];
        #pragma unroll
        for (int r = 0; r < 8; ++r) {
            acc0[r] = fmaf(xr[r], w0, acc0[r]);
            acc1[r] = fmaf(xr[r], w1, acc1[r]);
        }
    }
    float b0 = bp[c], b1 = bp[c + 64];
    #pragma unroll
    for (int r = 0; r < 8; ++r) {
        long n = r0 + r8 + r;
        out[n * 128 + c]      = acc0[r] + b0;
        out[n * 128 + c + 64] = acc1[r] + b1;
    }
}

extern "C" void kernel_launch(void* const* d_in, const int* in_sizes, int n_in,
                              void* d_out, int out_size, void* d_ws, size_t ws_size,
                              hipStream_t stream)
{
    const float* x  = (const float*)d_in[0];
    const float* Wq = (const float*)d_in[1];
    const float* bq = (const float*)d_in[2];
    const float* Wp = (const float*)d_in[3];
    const float* bp = (const float*)d_in[4];
    float* out = (float*)d_out;

    // workspace: Q (4MB) | KF (4MB) | VF (4MB) | attn-out (4MB), all bf16
    unsigned short* Qw  = (unsigned short*)d_ws;
    unsigned short* KFw = Qw  + (size_t)16 * 4096 * 32;
    unsigned short* VFw = KFw + (size_t)16 * 4096 * 32;
    unsigned short* AOw = VFw + (size_t)16 * 4096 * 32;

    qkv_kernel<<<512, 256, 0, stream>>>(x, Wq, bq, Qw, KFw, VFw);
    attn_kernel<<<512, 256, 0, stream>>>(Qw, KFw, VFw, AOw);
    proj_kernel<<<512, 256, 0, stream>>>(AOw, Wp, bp, out);
}

// Round 4
// 101.437 us; speedup vs baseline: 2.4492x; 1.3517x over previous
//
#include <hip/hip_runtime.h>
#include <stdint.h>

#define N_SEQ 4096

typedef float f32x4 __attribute__((ext_vector_type(4)));
typedef float f32x2 __attribute__((ext_vector_type(2)));
typedef unsigned short u16x8 __attribute__((ext_vector_type(8)));
typedef unsigned short u16x4 __attribute__((ext_vector_type(4)));
typedef unsigned int u32x2 __attribute__((ext_vector_type(2)));
typedef __bf16 bf16x8 __attribute__((ext_vector_type(8)));

static __device__ __forceinline__ float bf2f(unsigned short u) {
    unsigned v = ((unsigned)u) << 16;
    return __builtin_bit_cast(float, v);
}

// ---------------- Kernel 1: QKV projection (fp32 GEMM, bf16 out) ----------------
// x[16384][128] @ Wq[128][384] + bq.
// Q  -> natural [bh][n][32], PRE-SCALED by SL = (1/sqrt(128))*log2(e)
// KF -> fragment-ready: KF[((bh*64+t)*4+ct)*512 + l*8 + i] = K[bh][64t+(l&15)+16ct][(l>>4)*8+i]
// VF -> fragment-ready, kv LINEAR (matches P LDS chunk order):
//       VF[(((bh*64+t)*2+kk)*2+dt)*512 + l*8 + i] = V[bh][64t+kv][(l&15)+16dt],
//       where kv = kk*32 + (l>>4)*8 + i
__global__ __launch_bounds__(256) void qkv_kernel(
    const float* __restrict__ x, const float* __restrict__ Wq,
    const float* __restrict__ bq, unsigned short* __restrict__ Qo,
    unsigned short* __restrict__ KFo, unsigned short* __restrict__ VFo)
{
    __shared__ __align__(16) float xT[128][36];   // [k][row]
    const int tid = threadIdx.x;
    const long r0 = (long)blockIdx.x * 32;
    const float SL = (float)(0.08838834764831845 * 1.4426950408889634);
    #pragma unroll
    for (int i = 0; i < 4; ++i) {
        int idx = i * 256 + tid;                   // 1024 float4 tiles
        int row = idx >> 5, kc = (idx & 31) * 4;
        f32x4 v = *(const f32x4*)&x[(r0 + row) * 128 + kc];
        xT[kc + 0][row] = v[0]; xT[kc + 1][row] = v[1];
        xT[kc + 2][row] = v[2]; xT[kc + 3][row] = v[3];
    }
    __syncthreads();
    const int r8 = (tid >> 6) * 8;    // 8-row group
    const int c6 = (tid & 63) * 6;    // 6 consecutive cols
    float acc[6][8];
    #pragma unroll
    for (int j = 0; j < 6; ++j)
        #pragma unroll
        for (int r = 0; r < 8; ++r) acc[j][r] = 0.f;

    for (int k = 0; k < 128; ++k) {
        f32x4 a0 = *(const f32x4*)&xT[k][r8];      // wave-uniform broadcast
        f32x4 a1 = *(const f32x4*)&xT[k][r8 + 4];
        float xr[8] = {a0[0],a0[1],a0[2],a0[3],a1[0],a1[1],a1[2],a1[3]};
        float wv[6];
        #pragma unroll
        for (int u = 0; u < 3; ++u) {
            f32x2 wp = *(const f32x2*)&Wq[k * 384 + c6 + 2 * u];
            wv[2*u] = wp[0]; wv[2*u+1] = wp[1];
        }
        #pragma unroll
        for (int j = 0; j < 6; ++j)
            #pragma unroll
            for (int r = 0; r < 8; ++r) acc[j][r] = fmaf(xr[r], wv[j], acc[j][r]);
    }
    #pragma unroll
    for (int j = 0; j < 6; ++j) {
        int col = c6 + j;
        int h = col / 96, rem = col % 96;
        int d = rem / 3, s = rem % 3;
        float bias = bq[col];
        #pragma unroll
        for (int r = 0; r < 8; ++r) {
            long n = r0 + r8 + r;
            int bb = (int)(n >> 12), nn = (int)(n & 4095);
            int bh = bb * 4 + h;
            int t = nn >> 6, kvi = nn & 63;
            float val = acc[j][r] + bias;
            if (s == 0) {
                unsigned short bits = __builtin_bit_cast(unsigned short, (__bf16)(val * SL));
                Qo[((long)bh * 4096 + nn) * 32 + d] = bits;
            } else if (s == 1) {
                unsigned short bits = __builtin_bit_cast(unsigned short, (__bf16)val);
                int ct = kvi >> 4, lo16 = kvi & 15;
                int gg = d >> 3, ii = d & 7;
                int l = gg * 16 + lo16;
                KFo[(long)(((bh * 64 + t) * 4 + ct) * 512) + l * 8 + ii] = bits;
            } else {
                unsigned short bits = __builtin_bit_cast(unsigned short, (__bf16)val);
                // kv LINEAR order (identity pos) to match attn's P-read chunks
                int kk = kvi >> 5, lg = (kvi >> 3) & 3, ii = kvi & 7;
                int l = lg * 16 + (d & 15);
                int dt = d >> 4;
                VFo[(long)((((bh * 64 + t) * 2 + kk) * 2 + dt) * 512) + l * 8 + ii] = bits;
            }
        }
    }
}

// ---------------- Kernel 2: flash attention, swapped QK^T + P-dbuf pipeline ----------------
#define MFMA16 __builtin_amdgcn_mfma_f32_16x16x32_bf16

__global__ __launch_bounds__(256, 2) void attn_kernel(
    const unsigned short* __restrict__ Q, const unsigned short* __restrict__ KF,
    const unsigned short* __restrict__ VF, unsigned short* __restrict__ AO)
{
    __shared__ __align__(16) unsigned short P_lds[4][2][2048]; // per-wave double-buffered P

    const int tid = threadIdx.x, lane = tid & 63, w = tid >> 6;
    const int g = lane >> 4, lo = lane & 15;

    // bijective XCD swizzle: consecutive-mod-8 blocks (same XCD) share bh
    const int bid = blockIdx.x;
    const int vid = (bid & 7) * 64 + (bid >> 3);
    const int qi = vid & 31, bh = vid >> 5;
    const int q0 = qi * 128 + w * 32;

    bf16x8 qf[2];
    #pragma unroll
    for (int rt = 0; rt < 2; ++rt) {
        const unsigned short* p = Q + ((long)bh * 4096 + q0 + rt * 16 + lo) * 32 + g * 8;
        qf[rt] = __builtin_bit_cast(bf16x8, *(const u16x8*)p);
    }
    bf16x8 onesf;
    {
        u16x8 ou = {0x3F80,0x3F80,0x3F80,0x3F80,0x3F80,0x3F80,0x3F80,0x3F80};
        onesf = __builtin_bit_cast(bf16x8, ou);
    }
    const f32x4 zf = {0.f, 0.f, 0.f, 0.f};
    f32x4 o_[2][2] = {{zf, zf}, {zf, zf}};
    f32x4 ls[2]    = {zf, zf};

    // LDS P layout: element kv of q-row q lives at short-offset
    //   q*64 + (((kv>>3) ^ (q&7)) * 8) + (kv & 7)     (16B-block XOR swizzle)
    // Swapped QK^T D-layout: s_[rt][ct][j] = S[q = 16rt + lo][kv = 16ct + 4g + j]
    int woff[2][4], roff[2][2];
    #pragma unroll
    for (int qt = 0; qt < 2; ++qt) {
        int q = lo + 16 * qt;
        #pragma unroll
        for (int ct = 0; ct < 4; ++ct) {
            int kvb = 16 * ct + 4 * g;
            woff[qt][ct] = q * 64 + (((kvb >> 3) ^ (q & 7)) * 8) + ((kvb >> 2) & 1) * 4;
        }
    }
    #pragma unroll
    for (int rt = 0; rt < 2; ++rt) {
        int q = lo + 16 * rt;
        #pragma unroll
        for (int kk = 0; kk < 2; ++kk)
            roff[rt][kk] = q * 64 + ((((4 * kk) + g) ^ (q & 7)) * 8);
    }
    unsigned short* B0 = &P_lds[w][0][0];
    unsigned short* B1 = &P_lds[w][1][0];

    const u16x8* kp = (const u16x8*)KF + (long)bh * 64 * 256 + lane; // 256 u16x8 per tile
    const u16x8* vp = (const u16x8*)VF + (long)bh * 64 * 256 + lane;

    u16x8 K0[4], K1[4], V0[4], V1[4];
    #pragma unroll
    for (int i = 0; i < 4; ++i) K0[i] = kp[i * 64];   // K(0)
    kp += 256;

// iteration t: prefetch K(t+1)->KN, V(t)->VC; read P(t-1) from BR; QK(t) with KC;
// PV(t-1) with VP; softmax(t) -> BW. sched_barrier pins P-write(t) before P-read(t) of t+1.
#define BODY(KC, KN, VP, VC, BW, BR, DOPV) do {                                \
    _Pragma("unroll")                                                          \
    for (int i = 0; i < 4; ++i) KN[i] = kp[i * 64];                            \
    kp += 256;                                                                 \
    _Pragma("unroll")                                                          \
    for (int i = 0; i < 4; ++i) VC[i] = vp[i * 64];                            \
    vp += 256;                                                                 \
    u16x8 pa_[2][2];                                                           \
    if (DOPV) {                                                                \
        _Pragma("unroll")                                                      \
        for (int kk = 0; kk < 2; ++kk)                                         \
            _Pragma("unroll")                                                  \
            for (int rt = 0; rt < 2; ++rt)                                     \
                pa_[kk][rt] = *(const u16x8*)&BR[roff[rt][kk]];                \
    }                                                                          \
    f32x4 s_[2][4];                                                            \
    _Pragma("unroll")                                                          \
    for (int ct = 0; ct < 4; ++ct) {                                           \
        bf16x8 kfr = __builtin_bit_cast(bf16x8, KC[ct]);                       \
        s_[0][ct] = MFMA16(kfr, qf[0], zf, 0, 0, 0);                           \
        s_[1][ct] = MFMA16(kfr, qf[1], zf, 0, 0, 0);                           \
    }                                                                          \
    if (DOPV) {                                                                \
        _Pragma("unroll")                                                      \
        for (int kk = 0; kk < 2; ++kk)                                         \
            _Pragma("unroll")                                                  \
            for (int rt = 0; rt < 2; ++rt) {                                   \
                bf16x8 paf = __builtin_bit_cast(bf16x8, pa_[kk][rt]);          \
                ls[rt] = MFMA16(paf, onesf, ls[rt], 0, 0, 0);                  \
                o_[rt][0] = MFMA16(paf, __builtin_bit_cast(bf16x8, VP[kk*2+0]),\
                                   o_[rt][0], 0, 0, 0);                        \
                o_[rt][1] = MFMA16(paf, __builtin_bit_cast(bf16x8, VP[kk*2+1]),\
                                   o_[rt][1], 0, 0, 0);                        \
            }                                                                  \
    }                                                                          \
    _Pragma("unroll")                                                          \
    for (int qt = 0; qt < 2; ++qt)                                             \
        _Pragma("unroll")                                                      \
        for (int ct = 0; ct < 4; ++ct) {                                       \
            unsigned b0 = __builtin_bit_cast(unsigned,                         \
                __builtin_amdgcn_exp2f(s_[qt][ct][0])) + 0x8000u;              \
            unsigned b1 = __builtin_bit_cast(unsigned,                         \
                __builtin_amdgcn_exp2f(s_[qt][ct][1])) + 0x8000u;              \
            unsigned b2 = __builtin_bit_cast(unsigned,                         \
                __builtin_amdgcn_exp2f(s_[qt][ct][2])) + 0x8000u;              \
            unsigned b3 = __builtin_bit_cast(unsigned,                         \
                __builtin_amdgcn_exp2f(s_[qt][ct][3])) + 0x8000u;              \
            u32x2 wv_;                                                         \
            wv_[0] = __builtin_amdgcn_perm(b1, b0, 0x07060302u);               \
            wv_[1] = __builtin_amdgcn_perm(b3, b2, 0x07060302u);               \
            *(u16x4*)&BW[woff[qt][ct]] = __builtin_bit_cast(u16x4, wv_);       \
        }                                                                      \
    __builtin_amdgcn_sched_barrier(0);                                         \
} while (0)

    BODY(K0, K1, V1, V0, B0, B1, 0);            // t = 0 (no PV yet)
    #pragma unroll 1
    for (int t = 1; t < 63; t += 2) {
        BODY(K1, K0, V0, V1, B1, B0, 1);        // odd t
        BODY(K0, K1, V1, V0, B0, B1, 1);        // even t+1
    }
    BODY(K1, K0, V0, V1, B1, B0, 1);            // t = 63 (prefetch overshoots: in-bounds ws, unused)
#undef BODY

    // final PV(63): P in B1, V(63) in V1
    #pragma unroll
    for (int kk = 0; kk < 2; ++kk)
        #pragma unroll
        for (int rt = 0; rt < 2; ++rt) {
            bf16x8 paf = __builtin_bit_cast(bf16x8, *(const u16x8*)&B1[roff[rt][kk]]);
            ls[rt] = MFMA16(paf, onesf, ls[rt], 0, 0, 0);
            o_[rt][0] = MFMA16(paf, __builtin_bit_cast(bf16x8, V1[kk*2+0]), o_[rt][0], 0, 0, 0);
            o_[rt][1] = MFMA16(paf, __builtin_bit_cast(bf16x8, V1[kk*2+1]), o_[rt][1], 0, 0, 0);
        }

    // epilogue: AO[b][n][h*32+d] bf16
    const int bb = bh >> 2, h = bh & 3;
    #pragma unroll
    for (int rt = 0; rt < 2; ++rt)
        #pragma unroll
        for (int j = 0; j < 4; ++j) {
            float rl = __builtin_amdgcn_rcpf(ls[rt][j]);
            int row = q0 + rt * 16 + 4 * g + j;
            #pragma unroll
            for (int dt = 0; dt < 2; ++dt) {
                int e = h * 32 + lo + 16 * dt;
                float val = o_[rt][dt][j] * rl;
                AO[((long)bb * N_SEQ + row) * 128 + e] =
                    __builtin_bit_cast(unsigned short, (__bf16)val);
            }
        }
}

// ---------------- Kernel 3: output projection (fp32 GEMM + bias) ----------------
__global__ __launch_bounds__(256) void proj_kernel(
    const unsigned short* __restrict__ ain, const float* __restrict__ Wp,
    const float* __restrict__ bp, float* __restrict__ out)
{
    __shared__ __align__(16) float xT[128][36];
    const int tid = threadIdx.x;
    const long r0 = (long)blockIdx.x * 32;
    #pragma unroll
    for (int i = 0; i < 2; ++i) {
        int idx = i * 256 + tid;                 // 512 x u16x8
        int row = idx >> 4, kc = (idx & 15) * 8;
        u16x8 v = *(const u16x8*)&ain[(r0 + row) * 128 + kc];
        #pragma unroll
        for (int e = 0; e < 8; ++e) xT[kc + e][row] = bf2f(v[e]);
    }
    __syncthreads();
    const int r8 = (tid >> 6) * 8;
    const int c  = tid & 63;
    float acc0[8], acc1[8];
    #pragma unroll
    for (int r = 0; r < 8; ++r) { acc0[r] = 0.f; acc1[r] = 0.f; }
    for (int k = 0; k < 128; ++k) {
        f32x4 a0 = *(const f32x4*)&xT[k][r8];
        f32x4 a1 = *(const f32x4*)&xT[k][r8 + 4];
        float xr[8] = {a0[0],a0[1],a0[2],a0[3],a1[0],a1[1],a1[2],a1[3]};
        float w0 = Wp[k * 128 + c];
        float w1 = Wp[k * 128 + c + 64];
        #pragma unroll
        for (int r = 0; r < 8; ++r) {
            acc0[r] = fmaf(xr[r], w0, acc0[r]);
            acc1[r] = fmaf(xr[r], w1, acc1[r]);
        }
    }
    float b0 = bp[c], b1 = bp[c + 64];
    #pragma unroll
    for (int r = 0; r < 8; ++r) {
        long n = r0 + r8 + r;
        out[n * 128 + c]      = acc0[r] + b0;
        out[n * 128 + c + 64] = acc1[r] + b1;
    }
}

extern "C" void kernel_launch(void* const* d_in, const int* in_sizes, int n_in,
                              void* d_out, int out_size, void* d_ws, size_t ws_size,
                              hipStream_t stream)
{
    const float* x  = (const float*)d_in[0];
    const float* Wq = (const float*)d_in[1];
    const float* bq = (const float*)d_in[2];
    const float* Wp = (const float*)d_in[3];
    const float* bp = (const float*)d_in[4];
    float* out = (float*)d_out;

    // workspace: Q (4MB) | KF (4MB) | VF (4MB) | attn-out (4MB), all bf16
    unsigned short* Qw  = (unsigned short*)d_ws;
    unsigned short* KFw = Qw  + (size_t)16 * 4096 * 32;
    unsigned short* VFw = KFw + (size_t)16 * 4096 * 32;
    unsigned short* AOw = VFw + (size_t)16 * 4096 * 32;

    qkv_kernel<<<512, 256, 0, stream>>>(x, Wq, bq, Qw, KFw, VFw);
    attn_kernel<<<512, 256, 0, stream>>>(Qw, KFw, VFw, AOw);
    proj_kernel<<<512, 256, 0, stream>>>(AOw, Wp, bp, out);
}